// Round 4
// baseline (167.741 us; speedup 1.0000x reference)
//
#include <hip/hip_runtime.h>
#include <math.h>

#define N_NODES 1024
#define DEG     24
#define K_NN    12
#define C_S     384
#define C_Z     128
#define C_G     16
#define N_RBF   64
#define N_EDGES (N_NODES*DEG)

typedef short short8 __attribute__((ext_vector_type(8)));
typedef float f32x4  __attribute__((ext_vector_type(4)));

__device__ __forceinline__ float sigf(float x) {
  return __builtin_amdgcn_rcpf(1.f + __expf(-x));
}

// float -> bf16 (RNE)
__device__ __forceinline__ short f2b(float x) {
  union { float f; unsigned u; } v; v.f = x;
  unsigned r = v.u + 0x7FFFu + ((v.u >> 16) & 1u);
  return (short)(r >> 16);
}
__device__ __forceinline__ float b2f(short s) {
  union { unsigned u; float f; } v; v.u = ((unsigned)(unsigned short)s) << 16;
  return v.f;
}

// ---------------- K1: nl = nf@wl+b, nr = nf@wr+b ----------------
__global__ __launch_bounds__(64) void k_nlr(
    const float* __restrict__ nf, const float* __restrict__ wl_w, const float* __restrict__ wl_b,
    const float* __restrict__ wr_w, const float* __restrict__ wr_b,
    float* __restrict__ nl, float* __restrict__ nr)
{
  __shared__ float row[C_S];
  int n = blockIdx.x, t = threadIdx.x;
  for (int j = t; j < C_S; j += 64) row[j] = nf[(size_t)n*C_S + j];
  __syncthreads();
  if (t < 32) {
    int c = t & 15;
    const float* w = (t < 16) ? wl_w : wr_w;
    float acc = (t < 16) ? wl_b[c] : wr_b[c];
    #pragma unroll 8
    for (int j = 0; j < C_S; ++j) acc += row[j] * w[j*C_G + c];
    ((t < 16) ? nl : nr)[n*C_G + c] = acc;
  }
}

// ---------------- K2: At[n][c][i] = sum_j nr[n][j]*dg_w[(i*16+j)][c]  (bf16, transposed) ----------------
__global__ __launch_bounds__(128) void k_A(
    const float* __restrict__ nr, const float* __restrict__ dg_w, short* __restrict__ At)
{
  __shared__ float nrs[C_G];
  int n = blockIdx.x, t = threadIdx.x;   // t = c
  if (t < C_G) nrs[t] = nr[n*C_G + t];
  __syncthreads();
  float acc[16];
  #pragma unroll
  for (int i = 0; i < 16; ++i) acc[i] = 0.f;
  for (int j = 0; j < 16; ++j) {
    float nv = nrs[j];
    #pragma unroll
    for (int i = 0; i < 16; ++i) acc[i] += nv * dg_w[(size_t)(i*C_G + j)*C_Z + t];
  }
  short8 o0, o1;
  #pragma unroll
  for (int i = 0; i < 8; ++i) { o0[i] = f2b(acc[i]); o1[i] = f2b(acc[8+i]); }
  *(short8*)&At[(size_t)n*2048 + t*16]     = o0;
  *(short8*)&At[(size_t)n*2048 + t*16 + 8] = o1;
}

// ---------------- K3: transpose 4 weight mats [128k][128n] f32 -> wT [n][k] bf16 ----------------
__global__ __launch_bounds__(256) void k_wt(
    const float* __restrict__ eg, const float* __restrict__ ep,
    const float* __restrict__ og, const float* __restrict__ lo,
    short* __restrict__ wT)
{
  __shared__ float tb[32][33];
  int b = blockIdx.x; int w = b >> 4; int tile = b & 15;
  int bi = tile >> 2, bj = tile & 3;
  const float* src = (w == 0) ? eg : (w == 1) ? ep : (w == 2) ? og : lo;
  short* dst = wT + w * 16384;
  int t = threadIdx.x; int c = t & 31, r0 = t >> 5;
  #pragma unroll
  for (int p = 0; p < 4; ++p) { int r = r0 + p*8; tb[r][c] = src[(bi*32 + r)*128 + bj*32 + c]; }
  __syncthreads();
  #pragma unroll
  for (int p = 0; p < 4; ++p) { int r = r0 + p*8; dst[(bj*32 + r)*128 + bi*32 + c] = f2b(tb[c][r]); }
}

// ---------------- K4: dpT[c][r] = dp_w[r][c] bf16, row stride 72 (16B-aligned rows) ----------------
__global__ __launch_bounds__(128) void k_dpt(
    const float* __restrict__ dp_w, short* __restrict__ dpT)
{
  int t = threadIdx.x;  // t = c (0..127)
  for (int r = 0; r < 72; ++r)
    dpT[t*72 + r] = (r < 64) ? f2b(dp_w[r*128 + t]) : (short)0;
}

// ---------------- K5: fused gates + pairs + out, one block per destination group ----------------
// Phase 1: LN(ef[24]) -> xn (bf16 LDS)
// Phase 2: waves 0/1: e2 = sig(xn@eg)*(xn@ep) -> e2s (f32 LDS); waves 2/3: ogs=sig(xn@og) -> ogss (bf16 LDS)
// Phase 3: per-wave 6 o's: gate3/rbf MFMA -> S -> U row -> in-wave LN -> Un (bf16 LDS)
// Phase 4: out = (Un @ lo_w + lo_b) * ogs -> global
__global__ __launch_bounds__(256, 3) void k_fused(
    const float* __restrict__ efin, const float* __restrict__ ln_w, const float* __restrict__ ln_b,
    const short* __restrict__ wT,   // eg | ep | og | lo, each 16384 bf16 [n][k]
    const float* __restrict__ eg_b, const float* __restrict__ ep_b, const float* __restrict__ og_b,
    const int* __restrict__ eidx, const float* __restrict__ pos,
    const float* __restrict__ nl, const short* __restrict__ At, const short* __restrict__ dpTg,
    const float* __restrict__ dg_b, const float* __restrict__ dp_b,
    const float* __restrict__ lno_w, const float* __restrict__ lno_b, const float* __restrict__ lo_b,
    float* __restrict__ out)
{
  __shared__ short xn[32*136];     // LN'd ef, rows 24-31 zero pad
  __shared__ float e2s[24*132];    // stride 132: grp row-step of 4 shifts banks by 16 -> 2-way max
  __shared__ short ogss[24*136];
  __shared__ short Un[32*136];     // LN'd U, rows 24-31 zero pad
  __shared__ short nlb[DEG*C_G];
  __shared__ float p4[DEG][4];
  __shared__ int   s24[DEG];

  int t = threadIdx.x, g = blockIdx.x;
  int wv = t >> 6, lane = t & 63, col = lane & 15, grp = lane >> 4;

  if (t < DEG) {
    int s = eidx[g*DEG + t];
    s24[t] = s;
    p4[t][0] = pos[s*3+0]; p4[t][1] = pos[s*3+1]; p4[t][2] = pos[s*3+2]; p4[t][3] = 0.f;
  }
  for (int v = t; v < 8*136; v += 256) { xn[24*136 + v] = 0; Un[24*136 + v] = 0; }
  __syncthreads();
  for (int v = t; v < DEG*C_G; v += 256)
    nlb[v] = f2b(nl[s24[v>>4]*C_G + (v & 15)]);

  // ---- Phase 1: LayerNorm ef -> xn ----
  if (t < 192) {
    int el = t >> 3, sub = t & 7, c0 = sub*16;
    float x[16];
    size_t ein = (size_t)(g*DEG + el) * C_Z + c0;
    #pragma unroll
    for (int q = 0; q < 4; ++q) {
      float4 v = *(const float4*)(efin + ein + q*4);
      x[q*4+0]=v.x; x[q*4+1]=v.y; x[q*4+2]=v.z; x[q*4+3]=v.w;
    }
    float s = 0.f;
    #pragma unroll
    for (int q = 0; q < 16; ++q) s += x[q];
    s += __shfl_xor(s,1); s += __shfl_xor(s,2); s += __shfl_xor(s,4);
    float mean = s * (1.f/128.f);
    float vs = 0.f;
    #pragma unroll
    for (int q = 0; q < 16; ++q) { float d = x[q]-mean; vs += d*d; }
    vs += __shfl_xor(vs,1); vs += __shfl_xor(vs,2); vs += __shfl_xor(vs,4);
    float rstd = rsqrtf(vs*(1.f/128.f) + 1e-5f);
    short* xw = &xn[el*136 + c0];
    #pragma unroll
    for (int q = 0; q < 16; ++q)
      xw[q] = f2b((x[q]-mean)*rstd*ln_w[c0+q] + ln_b[c0+q]);
  }
  __syncthreads();

  // ---- Phase 2: gate GEMVs ----
  {
    int mtile = wv & 1;
    short8 a[4];
    const short* xr = &xn[(mtile*16 + col)*136];
    #pragma unroll
    for (int ks = 0; ks < 4; ++ks) a[ks] = *(const short8*)(xr + ks*32 + grp*8);
    if (wv < 2) {
      float egb[8], epb[8];
      #pragma unroll
      for (int t8 = 0; t8 < 8; ++t8) { int c = col+16*t8; egb[t8]=eg_b[c]; epb[t8]=ep_b[c]; }
      f32x4 acc[8], sg[8];
      #pragma unroll
      for (int t8 = 0; t8 < 8; ++t8) acc[t8] = (f32x4){0.f,0.f,0.f,0.f};
      #pragma unroll
      for (int ks = 0; ks < 4; ++ks)
        #pragma unroll
        for (int t8 = 0; t8 < 8; ++t8) {
          short8 b = *(const short8*)(wT + (size_t)(col+16*t8)*128 + ks*32 + grp*8);
          acc[t8] = __builtin_amdgcn_mfma_f32_16x16x32_bf16(a[ks], b, acc[t8], 0, 0, 0);
        }
      #pragma unroll
      for (int t8 = 0; t8 < 8; ++t8)
        #pragma unroll
        for (int r = 0; r < 4; ++r) sg[t8][r] = sigf(acc[t8][r] + egb[t8]);
      #pragma unroll
      for (int t8 = 0; t8 < 8; ++t8) acc[t8] = (f32x4){0.f,0.f,0.f,0.f};
      #pragma unroll
      for (int ks = 0; ks < 4; ++ks)
        #pragma unroll
        for (int t8 = 0; t8 < 8; ++t8) {
          short8 b = *(const short8*)(wT + 16384 + (size_t)(col+16*t8)*128 + ks*32 + grp*8);
          acc[t8] = __builtin_amdgcn_mfma_f32_16x16x32_bf16(a[ks], b, acc[t8], 0, 0, 0);
        }
      #pragma unroll
      for (int t8 = 0; t8 < 8; ++t8)
        #pragma unroll
        for (int r = 0; r < 4; ++r) {
          int e = mtile*16 + grp*4 + r;
          if (e < DEG) e2s[e*132 + col + 16*t8] = sg[t8][r] * (acc[t8][r] + epb[t8]);
        }
    } else {
      float ogb[8];
      #pragma unroll
      for (int t8 = 0; t8 < 8; ++t8) ogb[t8] = og_b[col+16*t8];
      f32x4 acc[8];
      #pragma unroll
      for (int t8 = 0; t8 < 8; ++t8) acc[t8] = (f32x4){0.f,0.f,0.f,0.f};
      #pragma unroll
      for (int ks = 0; ks < 4; ++ks)
        #pragma unroll
        for (int t8 = 0; t8 < 8; ++t8) {
          short8 b = *(const short8*)(wT + 32768 + (size_t)(col+16*t8)*128 + ks*32 + grp*8);
          acc[t8] = __builtin_amdgcn_mfma_f32_16x16x32_bf16(a[ks], b, acc[t8], 0, 0, 0);
        }
      #pragma unroll
      for (int t8 = 0; t8 < 8; ++t8)
        #pragma unroll
        for (int r = 0; r < 4; ++r) {
          int e = mtile*16 + grp*4 + r;
          if (e < DEG) ogss[e*136 + col + 16*t8] = f2b(sigf(acc[t8][r] + ogb[t8]));
        }
    }
  }
  __syncthreads();

  // ---- Phase 3: pairs (wave wv owns o = wv*6..wv*6+5) ----
  {
    float dgb[8], dpb[8];
    #pragma unroll
    for (int t8 = 0; t8 < 8; ++t8) { int c = col+16*t8; dgb[t8] = dg_b[c]; dpb[t8] = dp_b[c]; }
    float lnow1 = lno_w[lane], lnow2 = lno_w[64+lane];
    float lnob1 = lno_b[lane], lnob2 = lno_b[64+lane];
    const float RS = 3.2f, MUS = 20.f/63.f;

    for (int jo = 0; jo < 6; ++jo) {
      int o = wv*6 + jo;
      int n2 = s24[o];
      int o2 = o - 1 - col; if (o2 < 0) o2 += DEG;
      bool vk = (col < K_NN);
      float d;
      {
        float dx = p4[o2][0]-p4[o][0]+1e-8f;
        float dy = p4[o2][1]-p4[o][1]+1e-8f;
        float dz = p4[o2][2]-p4[o][2]+1e-8f;
        d = vk ? sqrtf(dx*dx+dy*dy+dz*dz) : 1.0e6f;
      }
      short8 a_nl = {0,0,0,0,0,0,0,0};
      if (vk && grp < 2) a_nl = *(const short8*)&nlb[o2*C_G + grp*8];
      short8 a_r0, a_r1;
      #pragma unroll
      for (int j = 0; j < 8; ++j) {
        float z0 = (d - (float)(grp*8 + j)*MUS)*RS;
        float z1 = (d - (float)(32 + grp*8 + j)*MUS)*RS;
        a_r0[j] = f2b(__expf(-z0*z0));
        a_r1[j] = f2b(__expf(-z1*z1));
      }
      f32x4 accg[8], accd[8];
      #pragma unroll
      for (int t8 = 0; t8 < 8; ++t8) { accg[t8] = (f32x4){0.f,0.f,0.f,0.f}; accd[t8] = (f32x4){0.f,0.f,0.f,0.f}; }
      const short8* Ab = (const short8*)(At + (size_t)n2*2048);
      short8 zz = {0,0,0,0,0,0,0,0};
      #pragma unroll
      for (int t8 = 0; t8 < 8; ++t8) {
        short8 b = (grp < 2) ? Ab[(col+16*t8)*2 + grp] : zz;
        accg[t8] = __builtin_amdgcn_mfma_f32_16x16x32_bf16(a_nl, b, accg[t8], 0, 0, 0);
      }
      #pragma unroll
      for (int t8 = 0; t8 < 8; ++t8) {
        const short* dbase = dpTg + (col+16*t8)*72 + grp*8;
        accd[t8] = __builtin_amdgcn_mfma_f32_16x16x32_bf16(a_r0, *(const short8*)dbase,      accd[t8], 0, 0, 0);
        accd[t8] = __builtin_amdgcn_mfma_f32_16x16x32_bf16(a_r1, *(const short8*)(dbase+32), accd[t8], 0, 0, 0);
      }
      float S[8];
      #pragma unroll
      for (int t8 = 0; t8 < 8; ++t8) {
        float sacc = 0.f;
        #pragma unroll
        for (int r = 0; r < 4; ++r)
          sacc += sigf(accg[t8][r] + dgb[t8]) * (accd[t8][r] + dpb[t8]);
        sacc = (grp == 3) ? 0.f : sacc;   // mask k rows 12..15
        sacc += __shfl_xor(sacc, 16); sacc += __shfl_xor(sacc, 32);
        S[t8] = sacc;
      }
      float v1 = S[0], v2 = S[4];
      if      (grp == 1) { v1 = S[1]; v2 = S[5]; }
      else if (grp == 2) { v1 = S[2]; v2 = S[6]; }
      else if (grp == 3) { v1 = S[3]; v2 = S[7]; }
      v1 *= e2s[o*132 + lane];
      v2 *= e2s[o*132 + 64 + lane];
      // in-wave LayerNorm of U row o
      float s = v1 + v2;
      s += __shfl_xor(s,1); s += __shfl_xor(s,2); s += __shfl_xor(s,4);
      s += __shfl_xor(s,8); s += __shfl_xor(s,16); s += __shfl_xor(s,32);
      float mean = s * (1.f/128.f);
      float d1 = v1 - mean, d2 = v2 - mean;
      float vs = d1*d1 + d2*d2;
      vs += __shfl_xor(vs,1); vs += __shfl_xor(vs,2); vs += __shfl_xor(vs,4);
      vs += __shfl_xor(vs,8); vs += __shfl_xor(vs,16); vs += __shfl_xor(vs,32);
      float rstd = rsqrtf(vs*(1.f/128.f) + 1e-5f);
      Un[o*136 + lane]      = f2b(d1*rstd*lnow1 + lnob1);
      Un[o*136 + 64 + lane] = f2b(d2*rstd*lnow2 + lnob2);
    }
  }
  __syncthreads();

  // ---- Phase 4: out = (Un @ lo_w + lo_b) * ogs ----
  {
    int omt = wv >> 1, nh = wv & 1;
    short8 ua[4];
    const short* ur = &Un[(omt*16 + col)*136];
    #pragma unroll
    for (int ks = 0; ks < 4; ++ks) ua[ks] = *(const short8*)(ur + ks*32 + grp*8);
    float lob[4];
    #pragma unroll
    for (int q = 0; q < 4; ++q) lob[q] = lo_b[col + 16*(nh*4+q)];
    f32x4 oacc[4];
    #pragma unroll
    for (int q = 0; q < 4; ++q) oacc[q] = (f32x4){0.f,0.f,0.f,0.f};
    #pragma unroll
    for (int ks = 0; ks < 4; ++ks)
      #pragma unroll
      for (int q = 0; q < 4; ++q) {
        int t8 = nh*4 + q;
        short8 b = *(const short8*)(wT + 49152 + (size_t)(col+16*t8)*128 + ks*32 + grp*8);
        oacc[q] = __builtin_amdgcn_mfma_f32_16x16x32_bf16(ua[ks], b, oacc[q], 0, 0, 0);
      }
    #pragma unroll
    for (int q = 0; q < 4; ++q)
      #pragma unroll
      for (int r = 0; r < 4; ++r) {
        int e = omt*16 + grp*4 + r;
        if (e < DEG) {
          int ch = col + 16*(nh*4+q);
          out[(size_t)(g*DEG + e)*C_Z + ch] = (oacc[q][r] + lob[q]) * b2f(ogss[e*136 + ch]);
        }
      }
  }
}

extern "C" void kernel_launch(void* const* d_in, const int* in_sizes, int n_in,
                              void* d_out, int out_size, void* d_ws, size_t ws_size,
                              hipStream_t stream)
{
  const float* nf    = (const float*)d_in[0];
  const float* pos   = (const float*)d_in[1];
  const float* efin  = (const float*)d_in[2];
  const float* ln_w  = (const float*)d_in[3];
  const float* ln_b  = (const float*)d_in[4];
  const float* wl_w  = (const float*)d_in[5];
  const float* wl_b  = (const float*)d_in[6];
  const float* wr_w  = (const float*)d_in[7];
  const float* wr_b  = (const float*)d_in[8];
  const float* ep_w  = (const float*)d_in[9];
  const float* ep_b  = (const float*)d_in[10];
  const float* eg_w  = (const float*)d_in[11];
  const float* eg_b  = (const float*)d_in[12];
  const float* dg_w  = (const float*)d_in[13];
  const float* dg_b  = (const float*)d_in[14];
  const float* dp_w  = (const float*)d_in[15];
  const float* dp_b  = (const float*)d_in[16];
  const float* lno_w = (const float*)d_in[17];
  const float* lno_b = (const float*)d_in[18];
  const float* lo_w  = (const float*)d_in[19];
  const float* lo_b  = (const float*)d_in[20];
  const float* og_w  = (const float*)d_in[21];
  const float* og_b  = (const float*)d_in[22];
  const int*   eidx  = (const int*)d_in[23];
  // d_in[24] = edge_edge_index: structure derived analytically, not read.

  float* ws   = (float*)d_ws;
  float* nlw  = ws;                                   // 16384 f32
  float* nrw  = ws + 16384;                           // 16384 f32
  short* Atw  = (short*)(ws + 32768);                 // 2,097,152 bf16
  short* dpTw = (short*)(ws + 32768 + 1048576);       // 9216 bf16
  short* wTw  = (short*)(ws + 32768 + 1048576 + 8192);// 65536 bf16 (eg,ep,og,lo)
  float* outp = (float*)d_out;

  k_nlr  <<<N_NODES, 64, 0, stream>>>(nf, wl_w, wl_b, wr_w, wr_b, nlw, nrw);
  k_A    <<<N_NODES, 128, 0, stream>>>(nrw, dg_w, Atw);
  k_wt   <<<64, 256, 0, stream>>>(eg_w, ep_w, og_w, lo_w, wTw);
  k_dpt  <<<1, 128, 0, stream>>>(dp_w, dpTw);
  k_fused<<<N_NODES, 256, 0, stream>>>(efin, ln_w, ln_b, wTw, eg_b, ep_b, og_b,
                                       eidx, pos, nlw, Atw, dpTw, dg_b, dp_b,
                                       lno_w, lno_b, lo_b, outp);
}

// Round 5
// 144.295 us; speedup vs baseline: 1.1625x; 1.1625x over previous
//
#include <hip/hip_runtime.h>
#include <math.h>

#define N_NODES 1024
#define DEG     24
#define K_NN    12
#define C_S     384
#define C_Z     128
#define C_G     16
#define N_RBF   64
#define N_EDGES (N_NODES*DEG)

typedef short short8 __attribute__((ext_vector_type(8)));
typedef float f32x4  __attribute__((ext_vector_type(4)));

__device__ __forceinline__ float sigf(float x) {
  return __builtin_amdgcn_rcpf(1.f + __expf(-x));
}

// float -> bf16 (RNE)
__device__ __forceinline__ short f2b(float x) {
  union { float f; unsigned u; } v; v.f = x;
  unsigned r = v.u + 0x7FFFu + ((v.u >> 16) & 1u);
  return (short)(r >> 16);
}
__device__ __forceinline__ float b2f(short s) {
  union { unsigned u; float f; } v; v.u = ((unsigned)(unsigned short)s) << 16;
  return v.f;
}

// ---------------- K1: nl = nf@wl+b, nr = nf@wr+b ----------------
__global__ __launch_bounds__(64) void k_nlr(
    const float* __restrict__ nf, const float* __restrict__ wl_w, const float* __restrict__ wl_b,
    const float* __restrict__ wr_w, const float* __restrict__ wr_b,
    float* __restrict__ nl, float* __restrict__ nr)
{
  __shared__ float row[C_S];
  int n = blockIdx.x, t = threadIdx.x;
  for (int j = t; j < C_S; j += 64) row[j] = nf[(size_t)n*C_S + j];
  __syncthreads();
  if (t < 32) {
    int c = t & 15;
    const float* w = (t < 16) ? wl_w : wr_w;
    float acc = (t < 16) ? wl_b[c] : wr_b[c];
    #pragma unroll 8
    for (int j = 0; j < C_S; ++j) acc += row[j] * w[j*C_G + c];
    ((t < 16) ? nl : nr)[n*C_G + c] = acc;
  }
}

// ---------------- K2: At[n][c][i] = sum_j nr[n][j]*dg_w[(i*16+j)][c]  (bf16, transposed) ----------------
__global__ __launch_bounds__(128) void k_A(
    const float* __restrict__ nr, const float* __restrict__ dg_w, short* __restrict__ At)
{
  __shared__ float nrs[C_G];
  int n = blockIdx.x, t = threadIdx.x;   // t = c
  if (t < C_G) nrs[t] = nr[n*C_G + t];
  __syncthreads();
  float acc[16];
  #pragma unroll
  for (int i = 0; i < 16; ++i) acc[i] = 0.f;
  for (int j = 0; j < 16; ++j) {
    float nv = nrs[j];
    #pragma unroll
    for (int i = 0; i < 16; ++i) acc[i] += nv * dg_w[(size_t)(i*C_G + j)*C_Z + t];
  }
  short8 o0, o1;
  #pragma unroll
  for (int i = 0; i < 8; ++i) { o0[i] = f2b(acc[i]); o1[i] = f2b(acc[8+i]); }
  *(short8*)&At[(size_t)n*2048 + t*16]     = o0;
  *(short8*)&At[(size_t)n*2048 + t*16 + 8] = o1;
}

// ---------------- K3: transpose 4 weight mats [128k][128n] f32 -> wT [n][k] bf16 ----------------
__global__ __launch_bounds__(256) void k_wt(
    const float* __restrict__ eg, const float* __restrict__ ep,
    const float* __restrict__ og, const float* __restrict__ lo,
    short* __restrict__ wT)
{
  __shared__ float tb[32][33];
  int b = blockIdx.x; int w = b >> 4; int tile = b & 15;
  int bi = tile >> 2, bj = tile & 3;
  const float* src = (w == 0) ? eg : (w == 1) ? ep : (w == 2) ? og : lo;
  short* dst = wT + w * 16384;
  int t = threadIdx.x; int c = t & 31, r0 = t >> 5;
  #pragma unroll
  for (int p = 0; p < 4; ++p) { int r = r0 + p*8; tb[r][c] = src[(bi*32 + r)*128 + bj*32 + c]; }
  __syncthreads();
  #pragma unroll
  for (int p = 0; p < 4; ++p) { int r = r0 + p*8; dst[(bj*32 + r)*128 + bi*32 + c] = f2b(tb[c][r]); }
}

// ---------------- K4: dpT[c][r] = dp_w[r][c] bf16, row stride 72 (16B-aligned rows) ----------------
__global__ __launch_bounds__(128) void k_dpt(
    const float* __restrict__ dp_w, short* __restrict__ dpT)
{
  int t = threadIdx.x;  // t = c (0..127)
  for (int r = 0; r < 72; ++r)
    dpT[t*72 + r] = (r < 64) ? f2b(dp_w[r*128 + t]) : (short)0;
}

// ---------------- K5: fused gates + pairs + out, one block per destination group ----------------
// waves_per_eu(4,4): pin VGPR budget to 128 — R4's (256,3) hint let the allocator
// target 6 waves/EU (84 VGPR) and spill ~100B/thread to scratch (WRITE_SIZE 3x output).
__global__ __launch_bounds__(256) __attribute__((amdgpu_waves_per_eu(4, 4))) void k_fused(
    const float* __restrict__ efin, const float* __restrict__ ln_w, const float* __restrict__ ln_b,
    const short* __restrict__ wT,   // eg | ep | og | lo, each 16384 bf16 [n][k]
    const float* __restrict__ eg_b, const float* __restrict__ ep_b, const float* __restrict__ og_b,
    const int* __restrict__ eidx, const float* __restrict__ pos,
    const float* __restrict__ nl, const short* __restrict__ At, const short* __restrict__ dpTg,
    const float* __restrict__ dg_b, const float* __restrict__ dp_b,
    const float* __restrict__ lno_w, const float* __restrict__ lno_b, const float* __restrict__ lo_b,
    float* __restrict__ out)
{
  __shared__ short xn[32*136];     // LN'd ef, rows 24-31 zero pad
  __shared__ float e2s[24*132];
  __shared__ short ogss[24*136];
  __shared__ short Un[32*136];     // LN'd U, rows 24-31 zero pad
  __shared__ short nlb[DEG*C_G];
  __shared__ float p4[DEG][4];
  __shared__ int   s24[DEG];

  int t = threadIdx.x, g = blockIdx.x;
  int wv = t >> 6, lane = t & 63, col = lane & 15, grp = lane >> 4;

  if (t < DEG) {
    int s = eidx[g*DEG + t];
    s24[t] = s;
    p4[t][0] = pos[s*3+0]; p4[t][1] = pos[s*3+1]; p4[t][2] = pos[s*3+2]; p4[t][3] = 0.f;
  }
  for (int v = t; v < 8*136; v += 256) { xn[24*136 + v] = 0; Un[24*136 + v] = 0; }
  __syncthreads();
  for (int v = t; v < DEG*C_G; v += 256)
    nlb[v] = f2b(nl[s24[v>>4]*C_G + (v & 15)]);

  // ---- Phase 1: LayerNorm ef -> xn ----
  if (t < 192) {
    int el = t >> 3, sub = t & 7, c0 = sub*16;
    float x[16];
    size_t ein = (size_t)(g*DEG + el) * C_Z + c0;
    #pragma unroll
    for (int q = 0; q < 4; ++q) {
      float4 v = *(const float4*)(efin + ein + q*4);
      x[q*4+0]=v.x; x[q*4+1]=v.y; x[q*4+2]=v.z; x[q*4+3]=v.w;
    }
    float s = 0.f;
    #pragma unroll
    for (int q = 0; q < 16; ++q) s += x[q];
    s += __shfl_xor(s,1); s += __shfl_xor(s,2); s += __shfl_xor(s,4);
    float mean = s * (1.f/128.f);
    float vs = 0.f;
    #pragma unroll
    for (int q = 0; q < 16; ++q) { float d = x[q]-mean; vs += d*d; }
    vs += __shfl_xor(vs,1); vs += __shfl_xor(vs,2); vs += __shfl_xor(vs,4);
    float rstd = rsqrtf(vs*(1.f/128.f) + 1e-5f);
    short* xw = &xn[el*136 + c0];
    #pragma unroll
    for (int q = 0; q < 16; ++q)
      xw[q] = f2b((x[q]-mean)*rstd*ln_w[c0+q] + ln_b[c0+q]);
  }
  __syncthreads();

  // ---- Phase 2: gate GEMVs (two 4-wide chunks to halve register pressure) ----
  {
    int mtile = wv & 1;
    short8 a[4];
    const short* xr = &xn[(mtile*16 + col)*136];
    #pragma unroll
    for (int ks = 0; ks < 4; ++ks) a[ks] = *(const short8*)(xr + ks*32 + grp*8);
    if (wv < 2) {
      #pragma unroll 1
      for (int h = 0; h < 2; ++h) {
        float egb[4], epb[4];
        #pragma unroll
        for (int q = 0; q < 4; ++q) { int c = col+16*(h*4+q); egb[q]=eg_b[c]; epb[q]=ep_b[c]; }
        f32x4 acc[4], sg[4];
        #pragma unroll
        for (int q = 0; q < 4; ++q) acc[q] = (f32x4){0.f,0.f,0.f,0.f};
        #pragma unroll
        for (int ks = 0; ks < 4; ++ks)
          #pragma unroll
          for (int q = 0; q < 4; ++q) {
            short8 b = *(const short8*)(wT + (size_t)(col+16*(h*4+q))*128 + ks*32 + grp*8);
            acc[q] = __builtin_amdgcn_mfma_f32_16x16x32_bf16(a[ks], b, acc[q], 0, 0, 0);
          }
        #pragma unroll
        for (int q = 0; q < 4; ++q)
          #pragma unroll
          for (int r = 0; r < 4; ++r) sg[q][r] = sigf(acc[q][r] + egb[q]);
        #pragma unroll
        for (int q = 0; q < 4; ++q) acc[q] = (f32x4){0.f,0.f,0.f,0.f};
        #pragma unroll
        for (int ks = 0; ks < 4; ++ks)
          #pragma unroll
          for (int q = 0; q < 4; ++q) {
            short8 b = *(const short8*)(wT + 16384 + (size_t)(col+16*(h*4+q))*128 + ks*32 + grp*8);
            acc[q] = __builtin_amdgcn_mfma_f32_16x16x32_bf16(a[ks], b, acc[q], 0, 0, 0);
          }
        #pragma unroll
        for (int q = 0; q < 4; ++q)
          #pragma unroll
          for (int r = 0; r < 4; ++r) {
            int e = mtile*16 + grp*4 + r;
            if (e < DEG) e2s[e*132 + col + 16*(h*4+q)] = sg[q][r] * (acc[q][r] + epb[q]);
          }
      }
    } else {
      #pragma unroll 1
      for (int h = 0; h < 2; ++h) {
        float ogb[4];
        #pragma unroll
        for (int q = 0; q < 4; ++q) ogb[q] = og_b[col+16*(h*4+q)];
        f32x4 acc[4];
        #pragma unroll
        for (int q = 0; q < 4; ++q) acc[q] = (f32x4){0.f,0.f,0.f,0.f};
        #pragma unroll
        for (int ks = 0; ks < 4; ++ks)
          #pragma unroll
          for (int q = 0; q < 4; ++q) {
            short8 b = *(const short8*)(wT + 32768 + (size_t)(col+16*(h*4+q))*128 + ks*32 + grp*8);
            acc[q] = __builtin_amdgcn_mfma_f32_16x16x32_bf16(a[ks], b, acc[q], 0, 0, 0);
          }
        #pragma unroll
        for (int q = 0; q < 4; ++q)
          #pragma unroll
          for (int r = 0; r < 4; ++r) {
            int e = mtile*16 + grp*4 + r;
            if (e < DEG) ogss[e*136 + col + 16*(h*4+q)] = f2b(sigf(acc[q][r] + ogb[q]));
          }
      }
    }
  }
  __syncthreads();

  // ---- Phase 3: pairs (wave wv owns o = wv*6..wv*6+5), two 4-wide chunks ----
  {
    f32x4 dgb_lo, dgb_hi, dpb_lo, dpb_hi;
    #pragma unroll
    for (int q = 0; q < 4; ++q) {
      dgb_lo[q] = dg_b[col+16*q];     dgb_hi[q] = dg_b[col+16*(4+q)];
      dpb_lo[q] = dp_b[col+16*q];     dpb_hi[q] = dp_b[col+16*(4+q)];
    }
    float lnow1 = lno_w[lane], lnow2 = lno_w[64+lane];
    float lnob1 = lno_b[lane], lnob2 = lno_b[64+lane];
    const float RS = 3.2f, MUS = 20.f/63.f;

    for (int jo = 0; jo < 6; ++jo) {
      int o = wv*6 + jo;
      int n2 = s24[o];
      int o2 = o - 1 - col; if (o2 < 0) o2 += DEG;
      bool vk = (col < K_NN);
      float d;
      {
        float dx = p4[o2][0]-p4[o][0]+1e-8f;
        float dy = p4[o2][1]-p4[o][1]+1e-8f;
        float dz = p4[o2][2]-p4[o][2]+1e-8f;
        d = vk ? sqrtf(dx*dx+dy*dy+dz*dz) : 1.0e6f;
      }
      short8 a_nl = {0,0,0,0,0,0,0,0};
      if (vk && grp < 2) a_nl = *(const short8*)&nlb[o2*C_G + grp*8];
      short8 a_r0, a_r1;
      #pragma unroll
      for (int j = 0; j < 8; ++j) {
        float z0 = (d - (float)(grp*8 + j)*MUS)*RS;
        float z1 = (d - (float)(32 + grp*8 + j)*MUS)*RS;
        a_r0[j] = f2b(__expf(-z0*z0));
        a_r1[j] = f2b(__expf(-z1*z1));
      }
      const short8* Ab = (const short8*)(At + (size_t)n2*2048);
      short8 zz = {0,0,0,0,0,0,0,0};

      auto chunk = [&](int t8base, f32x4 dgb, f32x4 dpb) -> float {
        f32x4 accg[4], accd[4];
        #pragma unroll
        for (int q = 0; q < 4; ++q) { accg[q] = (f32x4){0.f,0.f,0.f,0.f}; accd[q] = (f32x4){0.f,0.f,0.f,0.f}; }
        #pragma unroll
        for (int q = 0; q < 4; ++q) {
          short8 b = (grp < 2) ? Ab[(col+16*(t8base+q))*2 + grp] : zz;
          accg[q] = __builtin_amdgcn_mfma_f32_16x16x32_bf16(a_nl, b, accg[q], 0, 0, 0);
        }
        #pragma unroll
        for (int q = 0; q < 4; ++q) {
          const short* dbase = dpTg + (col+16*(t8base+q))*72 + grp*8;
          accd[q] = __builtin_amdgcn_mfma_f32_16x16x32_bf16(a_r0, *(const short8*)dbase,      accd[q], 0, 0, 0);
          accd[q] = __builtin_amdgcn_mfma_f32_16x16x32_bf16(a_r1, *(const short8*)(dbase+32), accd[q], 0, 0, 0);
        }
        float Sv[4];
        #pragma unroll
        for (int q = 0; q < 4; ++q) {
          float sacc = 0.f;
          #pragma unroll
          for (int r = 0; r < 4; ++r)
            sacc += sigf(accg[q][r] + dgb[q]) * (accd[q][r] + dpb[q]);
          sacc = (grp == 3) ? 0.f : sacc;   // mask k rows 12..15
          sacc += __shfl_xor(sacc, 16); sacc += __shfl_xor(sacc, 32);
          Sv[q] = sacc;
        }
        return (grp == 0) ? Sv[0] : (grp == 1) ? Sv[1] : (grp == 2) ? Sv[2] : Sv[3];
      };
      float v1 = chunk(0, dgb_lo, dpb_lo);
      float v2 = chunk(4, dgb_hi, dpb_hi);

      v1 *= e2s[o*132 + lane];
      v2 *= e2s[o*132 + 64 + lane];
      // in-wave LayerNorm of U row o
      float s = v1 + v2;
      s += __shfl_xor(s,1); s += __shfl_xor(s,2); s += __shfl_xor(s,4);
      s += __shfl_xor(s,8); s += __shfl_xor(s,16); s += __shfl_xor(s,32);
      float mean = s * (1.f/128.f);
      float d1 = v1 - mean, d2 = v2 - mean;
      float vs = d1*d1 + d2*d2;
      vs += __shfl_xor(vs,1); vs += __shfl_xor(vs,2); vs += __shfl_xor(vs,4);
      vs += __shfl_xor(vs,8); vs += __shfl_xor(vs,16); vs += __shfl_xor(vs,32);
      float rstd = rsqrtf(vs*(1.f/128.f) + 1e-5f);
      Un[o*136 + lane]      = f2b(d1*rstd*lnow1 + lnob1);
      Un[o*136 + 64 + lane] = f2b(d2*rstd*lnow2 + lnob2);
    }
  }
  __syncthreads();

  // ---- Phase 4: out = (Un @ lo_w + lo_b) * ogs ----
  {
    int omt = wv >> 1, nh = wv & 1;
    short8 ua[4];
    const short* ur = &Un[(omt*16 + col)*136];
    #pragma unroll
    for (int ks = 0; ks < 4; ++ks) ua[ks] = *(const short8*)(ur + ks*32 + grp*8);
    float lob[4];
    #pragma unroll
    for (int q = 0; q < 4; ++q) lob[q] = lo_b[col + 16*(nh*4+q)];
    f32x4 oacc[4];
    #pragma unroll
    for (int q = 0; q < 4; ++q) oacc[q] = (f32x4){0.f,0.f,0.f,0.f};
    #pragma unroll
    for (int ks = 0; ks < 4; ++ks)
      #pragma unroll
      for (int q = 0; q < 4; ++q) {
        int t8 = nh*4 + q;
        short8 b = *(const short8*)(wT + 49152 + (size_t)(col+16*t8)*128 + ks*32 + grp*8);
        oacc[q] = __builtin_amdgcn_mfma_f32_16x16x32_bf16(ua[ks], b, oacc[q], 0, 0, 0);
      }
    #pragma unroll
    for (int q = 0; q < 4; ++q)
      #pragma unroll
      for (int r = 0; r < 4; ++r) {
        int e = omt*16 + grp*4 + r;
        if (e < DEG) {
          int ch = col + 16*(nh*4+q);
          out[(size_t)(g*DEG + e)*C_Z + ch] = (oacc[q][r] + lob[q]) * b2f(ogss[e*136 + ch]);
        }
      }
  }
}

extern "C" void kernel_launch(void* const* d_in, const int* in_sizes, int n_in,
                              void* d_out, int out_size, void* d_ws, size_t ws_size,
                              hipStream_t stream)
{
  const float* nf    = (const float*)d_in[0];
  const float* pos   = (const float*)d_in[1];
  const float* efin  = (const float*)d_in[2];
  const float* ln_w  = (const float*)d_in[3];
  const float* ln_b  = (const float*)d_in[4];
  const float* wl_w  = (const float*)d_in[5];
  const float* wl_b  = (const float*)d_in[6];
  const float* wr_w  = (const float*)d_in[7];
  const float* wr_b  = (const float*)d_in[8];
  const float* ep_w  = (const float*)d_in[9];
  const float* ep_b  = (const float*)d_in[10];
  const float* eg_w  = (const float*)d_in[11];
  const float* eg_b  = (const float*)d_in[12];
  const float* dg_w  = (const float*)d_in[13];
  const float* dg_b  = (const float*)d_in[14];
  const float* dp_w  = (const float*)d_in[15];
  const float* dp_b  = (const float*)d_in[16];
  const float* lno_w = (const float*)d_in[17];
  const float* lno_b = (const float*)d_in[18];
  const float* lo_w  = (const float*)d_in[19];
  const float* lo_b  = (const float*)d_in[20];
  const float* og_w  = (const float*)d_in[21];
  const float* og_b  = (const float*)d_in[22];
  const int*   eidx  = (const int*)d_in[23];
  // d_in[24] = edge_edge_index: structure derived analytically, not read.

  float* ws   = (float*)d_ws;
  float* nlw  = ws;                                   // 16384 f32
  float* nrw  = ws + 16384;                           // 16384 f32
  short* Atw  = (short*)(ws + 32768);                 // 2,097,152 bf16
  short* dpTw = (short*)(ws + 32768 + 1048576);       // 9216 bf16
  short* wTw  = (short*)(ws + 32768 + 1048576 + 8192);// 65536 bf16 (eg,ep,og,lo)
  float* outp = (float*)d_out;

  k_nlr  <<<N_NODES, 64, 0, stream>>>(nf, wl_w, wl_b, wr_w, wr_b, nlw, nrw);
  k_A    <<<N_NODES, 128, 0, stream>>>(nrw, dg_w, Atw);
  k_wt   <<<64, 256, 0, stream>>>(eg_w, ep_w, og_w, lo_w, wTw);
  k_dpt  <<<1, 128, 0, stream>>>(dp_w, dpTw);
  k_fused<<<N_NODES, 256, 0, stream>>>(efin, ln_w, ln_b, wTw, eg_b, ep_b, og_b,
                                       eidx, pos, nlw, Atw, dpTw, dg_b, dp_b,
                                       lno_w, lno_b, lo_b, outp);
}